// Round 1
// baseline (55.086 us; speedup 1.0000x reference)
//
#include <hip/hip_runtime.h>
#include <hip/hip_bf16.h>

#define BB 64
#define SS 512
#define HH 1024
#define LL 9

// Kernel 1: per-batch-row stable compaction index.
// One block per batch row, 512 threads (8 waves). Inclusive scan of mask,
// scatter source index to its compacted position, write n_valid.
__global__ __launch_bounds__(512) void compact_idx_kernel(
    const int* __restrict__ mask, int* __restrict__ gidx, int* __restrict__ nvalid) {
    const int b = blockIdx.x;
    const int t = threadIdx.x;          // 0..511
    const int lane = t & 63;
    const int wid  = t >> 6;            // 0..7

    const int m = mask[b * SS + t];

    // wave-level inclusive scan
    int v = m;
    #pragma unroll
    for (int off = 1; off < 64; off <<= 1) {
        int u = __shfl_up(v, off, 64);
        if (lane >= off) v += u;
    }

    __shared__ int wsums[8];
    if (lane == 63) wsums[wid] = v;
    __syncthreads();

    int wbase = 0;
    for (int w = 0; w < wid; ++w) wbase += wsums[w];
    const int incl = v + wbase;
    const int excl = incl - m;

    if (m) gidx[b * SS + excl] = t;
    if (t == SS - 1) nvalid[b] = incl;
}

// Kernel 2: logits = x[gathered] @ W + bias; softmax over 9 labels.
// One wave per output row. W staged transposed in LDS (36 KB).
__global__ __launch_bounds__(256) void gemm_softmax_kernel(
    const float* __restrict__ x, const float* __restrict__ W,
    const float* __restrict__ bias, const int* __restrict__ gidx,
    const int* __restrict__ nvalid, float* __restrict__ out) {
    __shared__ float Wt[LL][HH];   // 36 KB, transposed: Wt[l][h] = W[h*LL + l]
    __shared__ float bsh[LL];

    for (int idx = threadIdx.x; idx < HH * LL; idx += blockDim.x) {
        const int h = idx / LL;
        const int l = idx - h * LL;
        Wt[l][h] = W[idx];         // coalesced global read
    }
    if (threadIdx.x < LL) bsh[threadIdx.x] = bias[threadIdx.x];
    __syncthreads();

    const int lane = threadIdx.x & 63;
    const int wid  = threadIdx.x >> 6;                 // 0..3
    const int nrows = BB * SS;
    const int wavesInGrid = gridDim.x * 4;

    for (int row = blockIdx.x * 4 + wid; row < nrows; row += wavesInGrid) {
        const int b = row >> 9;        // / SS
        const int p = row & (SS - 1);  // % SS

        float acc[LL];
        const bool pad = (p >= nvalid[b]);   // wave-uniform

        if (!pad) {
            const int src = gidx[row];
            const float4* xr = reinterpret_cast<const float4*>(
                x + ((size_t)b * SS + (size_t)src) * HH);
            #pragma unroll
            for (int l = 0; l < LL; ++l) acc[l] = 0.f;
            #pragma unroll
            for (int c = 0; c < 4; ++c) {
                const float4 xv = xr[c * 64 + lane];    // coalesced: 1 KB/wave/instr
                const int hbase = (c * 64 + lane) * 4;
                #pragma unroll
                for (int l = 0; l < LL; ++l) {
                    const float4 wv = *reinterpret_cast<const float4*>(&Wt[l][hbase]);
                    acc[l] += xv.x * wv.x + xv.y * wv.y + xv.z * wv.z + xv.w * wv.w;
                }
            }
            // butterfly reduce across 64 lanes; every lane ends with full sum
            #pragma unroll
            for (int l = 0; l < LL; ++l) {
                #pragma unroll
                for (int off = 32; off; off >>= 1)
                    acc[l] += __shfl_xor(acc[l], off, 64);
                acc[l] += bsh[l];
            }
        } else {
            #pragma unroll
            for (int l = 0; l < LL; ++l) acc[l] = bsh[l];
        }

        // softmax over the 9 logits (all lanes hold all 9)
        float mx = acc[0];
        #pragma unroll
        for (int l = 1; l < LL; ++l) mx = fmaxf(mx, acc[l]);
        float s = 0.f;
        #pragma unroll
        for (int l = 0; l < LL; ++l) { acc[l] = __expf(acc[l] - mx); s += acc[l]; }
        const float inv = 1.f / s;

        if (lane < LL) {
            float vsel = acc[0];
            #pragma unroll
            for (int l = 1; l < LL; ++l) if (lane == l) vsel = acc[l];
            out[(size_t)row * LL + lane] = vsel * inv;
        }
    }
}

extern "C" void kernel_launch(void* const* d_in, const int* in_sizes, int n_in,
                              void* d_out, int out_size, void* d_ws, size_t ws_size,
                              hipStream_t stream) {
    const float* x    = (const float*)d_in[0];   // [B,S,H] f32
    const int*   mask = (const int*)d_in[1];     // [B,S] i32
    const float* W    = (const float*)d_in[2];   // [H,L] f32
    const float* bias = (const float*)d_in[3];   // [L] f32
    float* out = (float*)d_out;                  // [B,S,L] f32

    int* gidx   = (int*)d_ws;                    // B*S ints
    int* nvalid = gidx + BB * SS;                // B ints

    compact_idx_kernel<<<BB, SS, 0, stream>>>(mask, gidx, nvalid);
    gemm_softmax_kernel<<<1024, 256, 0, stream>>>(x, W, bias, gidx, nvalid, out);
}

// Round 2
// 37.338 us; speedup vs baseline: 1.4753x; 1.4753x over previous
//
#include <hip/hip_runtime.h>
#include <hip/hip_bf16.h>

#define BB 64
#define SS 512
#define HH 1024
#define LL 9

// Kernel 1: per-batch-row stable compaction index (unchanged; verified R1).
__global__ __launch_bounds__(512) void compact_idx_kernel(
    const int* __restrict__ mask, int* __restrict__ gidx, int* __restrict__ nvalid) {
    const int b = blockIdx.x;
    const int t = threadIdx.x;          // 0..511
    const int lane = t & 63;
    const int wid  = t >> 6;            // 0..7

    const int m = mask[b * SS + t];

    int v = m;
    #pragma unroll
    for (int off = 1; off < 64; off <<= 1) {
        int u = __shfl_up(v, off, 64);
        if (lane >= off) v += u;
    }

    __shared__ int wsums[8];
    if (lane == 63) wsums[wid] = v;
    __syncthreads();

    int wbase = 0;
    for (int w = 0; w < wid; ++w) wbase += wsums[w];
    const int incl = v + wbase;
    const int excl = incl - m;

    if (m) gidx[b * SS + excl] = t;
    if (t == SS - 1) nvalid[b] = incl;
}

// DPP row_shr shift-add: after ctrl {1,2,4,8}, lane 15 of each 16-lane row
// holds the sum of all 16 lanes. VALU-rate, no LDS pipe.
template <int CTRL>
__device__ __forceinline__ float dpp_add(float v) {
    int s = __builtin_bit_cast(int, v);
    int r = __builtin_amdgcn_update_dpp(0, s, CTRL, 0xF, 0xF, true);
    return v + __builtin_bit_cast(float, r);
}

// Kernel 2: 16-lane group per 2 rows; W ds_reads broadcast across 4 groups
// and amortized over 2 rows each; DPP reduce; coalesced output via LDS.
__global__ __launch_bounds__(256) void gemm_softmax_kernel(
    const float* __restrict__ x, const float* __restrict__ W,
    const float* __restrict__ bias, const int* __restrict__ gidx,
    const int* __restrict__ nvalid, float* __restrict__ out) {
    __shared__ __align__(16) float Wt[LL][HH];   // 36 KB, Wt[l][h] = W[h*LL+l]
    __shared__ float obuf[288];                  // 32 rows * 9 labels per block
    __shared__ float bsh[LL];

    const int tid = threadIdx.x;
    for (int idx = tid; idx < HH * LL; idx += 256) {
        const int h = idx / LL;
        const int l = idx - h * LL;
        Wt[l][h] = W[idx];
    }
    if (tid < LL) bsh[tid] = bias[tid];
    __syncthreads();

    const int lane = tid & 63;
    const int w    = tid >> 6;        // wave 0..3
    const int g    = lane >> 4;       // group 0..3
    const int k    = lane & 15;       // lane-in-group

    const int gw   = blockIdx.x * 4 + w;   // 0..4095, one pass per wave
    const int row0 = gw * 8 + g * 2;       // group's first row (8 rows/wave)
    const int b    = row0 >> 9;            // batch (uniform per wave)
    const int nv   = nvalid[b];

    float acc[2][LL];
    #pragma unroll
    for (int r = 0; r < 2; ++r)
        #pragma unroll
        for (int l = 0; l < LL; ++l) acc[r][l] = 0.f;

    const float4* xr[2];
    float sc[2];
    #pragma unroll
    for (int r = 0; r < 2; ++r) {
        const int row = row0 + r;
        const int p = row & (SS - 1);
        const bool valid = (p < nv);
        const int src = valid ? gidx[row] : 0;  // pad rows read row 0 (L1 hit), scaled by 0
        sc[r] = valid ? 1.f : 0.f;
        xr[r] = reinterpret_cast<const float4*>(x + ((size_t)b * SS + src) * HH);
    }

    #pragma unroll 4
    for (int c = 0; c < 16; ++c) {
        const float4 xv0 = xr[0][c * 16 + k];   // 4x 256B segments per instr
        const float4 xv1 = xr[1][c * 16 + k];
        #pragma unroll
        for (int l = 0; l < LL; ++l) {
            const float4 wv = *reinterpret_cast<const float4*>(&Wt[l][(c * 16 + k) * 4]);
            acc[0][l] += xv0.x * wv.x + xv0.y * wv.y + xv0.z * wv.z + xv0.w * wv.w;
            acc[1][l] += xv1.x * wv.x + xv1.y * wv.y + xv1.z * wv.z + xv1.w * wv.w;
        }
    }

    // reduce each acc across the 16-lane group (lane k==15 gets the total)
    #pragma unroll
    for (int r = 0; r < 2; ++r)
        #pragma unroll
        for (int l = 0; l < LL; ++l) {
            float v = acc[r][l];
            v = dpp_add<0x111>(v);
            v = dpp_add<0x112>(v);
            v = dpp_add<0x114>(v);
            v = dpp_add<0x118>(v);
            acc[r][l] = v;
        }

    if (k == 15) {
        #pragma unroll
        for (int r = 0; r < 2; ++r) {
            float lg[LL];
            float mx = -3.0e38f;
            #pragma unroll
            for (int l = 0; l < LL; ++l) {
                lg[l] = acc[r][l] * sc[r] + bsh[l];
                mx = fmaxf(mx, lg[l]);
            }
            float s = 0.f;
            #pragma unroll
            for (int l = 0; l < LL; ++l) { lg[l] = __expf(lg[l] - mx); s += lg[l]; }
            const float inv = 1.f / s;
            const int ob = w * 72 + (g * 2 + r) * 9;
            #pragma unroll
            for (int l = 0; l < LL; ++l) obuf[ob + l] = lg[l] * inv;
        }
    }
    __syncthreads();

    // block covers 32 consecutive rows -> 288 contiguous floats
    const int base = blockIdx.x * 288;
    for (int t = tid; t < 288; t += 256) out[base + t] = obuf[t];
}

extern "C" void kernel_launch(void* const* d_in, const int* in_sizes, int n_in,
                              void* d_out, int out_size, void* d_ws, size_t ws_size,
                              hipStream_t stream) {
    const float* x    = (const float*)d_in[0];   // [B,S,H] f32
    const int*   mask = (const int*)d_in[1];     // [B,S] i32
    const float* W    = (const float*)d_in[2];   // [H,L] f32
    const float* bias = (const float*)d_in[3];   // [L] f32
    float* out = (float*)d_out;                  // [B,S,L] f32

    int* gidx   = (int*)d_ws;                    // B*S ints
    int* nvalid = gidx + BB * SS;                // B ints

    compact_idx_kernel<<<BB, SS, 0, stream>>>(mask, gidx, nvalid);
    gemm_softmax_kernel<<<1024, 256, 0, stream>>>(x, W, bias, gidx, nvalid, out);
}

// Round 3
// 33.919 us; speedup vs baseline: 1.6240x; 1.1008x over previous
//
#include <hip/hip_runtime.h>
#include <hip/hip_bf16.h>

#define BB 64
#define SS 512
#define HH 1024
#define LL 9

// DPP row_shr shift-add: after ctrl {1,2,4,8}, lane 15 of each 16-lane row
// holds the sum of all 16 lanes. VALU-rate, no LDS pipe. (verified R2)
template <int CTRL>
__device__ __forceinline__ float dpp_add(float v) {
    int s = __builtin_bit_cast(int, v);
    int r = __builtin_amdgcn_update_dpp(0, s, CTRL, 0xF, 0xF, true);
    return v + __builtin_bit_cast(float, r);
}

// Fully fused: per-block mask scan (compaction) + gather-GEMM + softmax.
// 512 blocks x 256 threads; block = 64 consecutive output rows of one batch.
// 4 rows per 16-lane group -> each W ds_read feeds 16 FMAs; all-pad waves
// (~half, since pads are the tail) skip loads/FMA/reduce entirely.
__global__ __launch_bounds__(256) void fused_ner_kernel(
    const float* __restrict__ x, const int* __restrict__ mask,
    const float* __restrict__ W, const float* __restrict__ bias,
    float* __restrict__ out) {
    __shared__ __align__(16) float Wt[LL][HH];  // 36 KB, Wt[l][h] = W[h*LL+l]
    __shared__ int gidx_sh[SS];                 // compacted pos -> src token
    __shared__ int wsum[4];
    __shared__ float bsh[LL];
    __shared__ float obuf[64 * LL];             // block's 64 rows staged

    const int tid = threadIdx.x;
    const int bat = blockIdx.x >> 3;            // 8 blocks per batch row
    const int seg = blockIdx.x & 7;
    const int lane = tid & 63;
    const int wv_  = tid >> 6;                  // wave 0..3

    // ---- stage W transposed (one-time, L2-hit for most blocks) ----
    for (int idx = tid; idx < HH * LL; idx += 256) {
        const int h = idx / LL;
        const int l = idx - h * LL;
        Wt[l][h] = W[idx];
    }
    if (tid < LL) bsh[tid] = bias[tid];

    // ---- in-block stable-compaction scan of this batch's 512 masks ----
    const int2 mm = reinterpret_cast<const int2*>(mask + bat * SS)[tid];
    const int m0 = mm.x, m1 = mm.y;
    const int s = m0 + m1;
    int incl = s;
    #pragma unroll
    for (int off = 1; off < 64; off <<= 1) {
        int u = __shfl_up(incl, off, 64);
        if (lane >= off) incl += u;
    }
    if (lane == 63) wsum[wv_] = incl;
    __syncthreads();                            // wsum ready; W writes fenced
    int wbase = 0;
    #pragma unroll
    for (int i = 0; i < 4; ++i) if (i < wv_) wbase += wsum[i];
    const int nv = wsum[0] + wsum[1] + wsum[2] + wsum[3];
    const int excl = incl - s + wbase;
    if (m0) gidx_sh[excl] = 2 * tid;
    if (m1) gidx_sh[excl + m0] = 2 * tid + 1;
    __syncthreads();                            // gidx_sh + Wt readable

    // ---- gather-GEMM: 16-lane group computes 4 rows ----
    const int g = lane >> 4;                    // group 0..3 (== DPP row)
    const int k = lane & 15;
    const int pw = seg * 64 + wv_ * 16;         // wave's first local p
    const int p0 = pw + g * 4;                  // group's first local p

    float acc[4][LL];
    #pragma unroll
    for (int r = 0; r < 4; ++r)
        #pragma unroll
        for (int l = 0; l < LL; ++l) acc[r][l] = 0.f;

    float sc[4];
    const float4* xr[4];
    #pragma unroll
    for (int r = 0; r < 4; ++r) {
        const int p = p0 + r;
        const bool valid = (p < nv);
        sc[r] = valid ? 1.f : 0.f;
        const int src = valid ? gidx_sh[p] : 0;     // clamp: never deref garbage
        xr[r] = reinterpret_cast<const float4*>(x + ((size_t)bat * SS + src) * HH);
    }

    if (pw < nv) {                              // wave-uniform: any real work?
        #pragma unroll 4
        for (int c = 0; c < 16; ++c) {
            const float4 xv0 = xr[0][c * 16 + k];
            const float4 xv1 = xr[1][c * 16 + k];
            const float4 xv2 = xr[2][c * 16 + k];
            const float4 xv3 = xr[3][c * 16 + k];
            #pragma unroll
            for (int l = 0; l < LL; ++l) {
                const float4 wvv = *reinterpret_cast<const float4*>(&Wt[l][(c * 16 + k) * 4]);
                acc[0][l] += xv0.x * wvv.x + xv0.y * wvv.y + xv0.z * wvv.z + xv0.w * wvv.w;
                acc[1][l] += xv1.x * wvv.x + xv1.y * wvv.y + xv1.z * wvv.z + xv1.w * wvv.w;
                acc[2][l] += xv2.x * wvv.x + xv2.y * wvv.y + xv2.z * wvv.z + xv2.w * wvv.w;
                acc[3][l] += xv3.x * wvv.x + xv3.y * wvv.y + xv3.z * wvv.z + xv3.w * wvv.w;
            }
        }
        // reduce across the 16-lane group; lane k==15 holds each total
        #pragma unroll
        for (int r = 0; r < 4; ++r)
            #pragma unroll
            for (int l = 0; l < LL; ++l) {
                float v = acc[r][l];
                v = dpp_add<0x111>(v);
                v = dpp_add<0x112>(v);
                v = dpp_add<0x114>(v);
                v = dpp_add<0x118>(v);
                acc[r][l] = v;
            }
    }

    if (k == 15) {
        #pragma unroll
        for (int r = 0; r < 4; ++r) {
            float lg[LL];
            float mx = -3.0e38f;
            #pragma unroll
            for (int l = 0; l < LL; ++l) {
                lg[l] = acc[r][l] * sc[r] + bsh[l];
                mx = fmaxf(mx, lg[l]);
            }
            float ssum = 0.f;
            #pragma unroll
            for (int l = 0; l < LL; ++l) { lg[l] = __expf(lg[l] - mx); ssum += lg[l]; }
            const float inv = 1.f / ssum;
            const int lp = wv_ * 16 + g * 4 + r;
            #pragma unroll
            for (int l = 0; l < LL; ++l) obuf[lp * LL + l] = lg[l] * inv;
        }
    }
    __syncthreads();

    // block's 64 rows are contiguous in out: 576 floats
    const int base = blockIdx.x * 64 * LL;
    for (int t = tid; t < 64 * LL; t += 256) out[base + t] = obuf[t];
}

extern "C" void kernel_launch(void* const* d_in, const int* in_sizes, int n_in,
                              void* d_out, int out_size, void* d_ws, size_t ws_size,
                              hipStream_t stream) {
    const float* x    = (const float*)d_in[0];   // [B,S,H] f32
    const int*   mask = (const int*)d_in[1];     // [B,S] i32
    const float* W    = (const float*)d_in[2];   // [H,L] f32
    const float* bias = (const float*)d_in[3];   // [L] f32
    float* out = (float*)d_out;                  // [B,S,L] f32

    fused_ner_kernel<<<BB * 8, 256, 0, stream>>>(x, mask, W, bias, out);
}

// Round 4
// 33.010 us; speedup vs baseline: 1.6688x; 1.0275x over previous
//
#include <hip/hip_runtime.h>
#include <hip/hip_bf16.h>

#define BB 64
#define SS 512
#define HH 1024
#define LL 9

// DPP row_shr shift-add: after ctrl {1,2,4,8}, lane 15 of each 16-lane row
// holds the sum of all 16 lanes. VALU-rate, no LDS pipe. (verified R2/R3)
template <int CTRL>
__device__ __forceinline__ float dpp_add(float v) {
    int s = __builtin_bit_cast(int, v);
    int r = __builtin_amdgcn_update_dpp(0, s, CTRL, 0xF, 0xF, true);
    return v + __builtin_bit_cast(float, r);
}

// Fused: per-block mask scan + gather-GEMM + softmax.
// 512 blocks x 256 threads; block = 64 consecutive output rows of one batch.
// W kept ROW-MAJOR in LDS (no transpose): lane reads its 4x9 sub-block as
// 9 contiguous ds_read_b128. Staged via async global_load_lds (width 16).
// Main loop: 3-deep explicit x prefetch ring.
__global__ __launch_bounds__(256) void fused_ner_kernel(
    const float* __restrict__ x, const int* __restrict__ mask,
    const float* __restrict__ W, const float* __restrict__ bias,
    float* __restrict__ out) {
    __shared__ __align__(16) float Wl[HH * LL];  // 36 KB, row-major W[h][l]
    __shared__ int gidx_sh[SS];                  // compacted pos -> src token
    __shared__ int wsum[4];
    __shared__ float bsh[LL];
    __shared__ float obuf[64 * LL];

    const int tid = threadIdx.x;
    const int bat = blockIdx.x >> 3;             // 8 blocks per batch row
    const int seg = blockIdx.x & 7;
    const int lane = tid & 63;
    const int wv_  = tid >> 6;                   // wave 0..3

    // ---- async stage W (row-major, no transform): 9x 16B per thread ----
    #pragma unroll
    for (int i = 0; i < 9; ++i) {
        const int f4 = i * 256 + tid;            // float4 index 0..2303
        __builtin_amdgcn_global_load_lds(
            (const __attribute__((address_space(1))) void*)(W + f4 * 4),
            (__attribute__((address_space(3))) void*)(&Wl[f4 * 4]),
            16, 0, 0);
    }
    if (tid < LL) bsh[tid] = bias[tid];

    // ---- in-block stable-compaction scan of this batch's 512 masks ----
    const int2 mm = reinterpret_cast<const int2*>(mask + bat * SS)[tid];
    const int m0 = mm.x, m1 = mm.y;
    const int s = m0 + m1;
    int incl = s;
    #pragma unroll
    for (int off = 1; off < 64; off <<= 1) {
        int u = __shfl_up(incl, off, 64);
        if (lane >= off) incl += u;
    }
    if (lane == 63) wsum[wv_] = incl;
    __syncthreads();                             // drains global_load_lds too
    int wbase = 0;
    #pragma unroll
    for (int i = 0; i < 4; ++i) if (i < wv_) wbase += wsum[i];
    const int nv = wsum[0] + wsum[1] + wsum[2] + wsum[3];
    const int excl = incl - s + wbase;
    if (m0) gidx_sh[excl] = 2 * tid;
    if (m1) gidx_sh[excl + m0] = 2 * tid + 1;
    __syncthreads();                             // gidx_sh readable

    // ---- gather-GEMM: 16-lane group computes 4 rows ----
    const int g = lane >> 4;                     // group 0..3 (== DPP row)
    const int k = lane & 15;
    const int pw = seg * 64 + wv_ * 16;          // wave's first local p
    const int p0 = pw + g * 4;

    float acc[4][LL];
    #pragma unroll
    for (int r = 0; r < 4; ++r)
        #pragma unroll
        for (int l = 0; l < LL; ++l) acc[r][l] = 0.f;

    float sc[4];
    const float4* xr[4];
    #pragma unroll
    for (int r = 0; r < 4; ++r) {
        const int p = p0 + r;
        const bool valid = (p < nv);
        sc[r] = valid ? 1.f : 0.f;
        const int src = valid ? gidx_sh[p] : 0;
        xr[r] = reinterpret_cast<const float4*>(x + ((size_t)bat * SS + src) * HH);
    }

    if (pw < nv) {                               // wave-uniform: any real work?
        float4 xv[4][4];                         // [slot][row] prefetch ring
        #pragma unroll
        for (int c = 0; c < 3; ++c)
            #pragma unroll
            for (int r = 0; r < 4; ++r) xv[c][r] = xr[r][c * 16 + k];

        #pragma unroll 4
        for (int c = 0; c < 16; ++c) {
            const int nc = (c + 3) & 15;         // wrap: tail reloads (L1-hit)
            #pragma unroll
            for (int r = 0; r < 4; ++r) xv[nc & 3][r] = xr[r][nc * 16 + k];

            // lane's 4x9 W sub-block: 36 contiguous floats, 9 ds_read_b128
            float4 wb[9];
            const float* wp = &Wl[(c * 16 + k) * 36];
            #pragma unroll
            for (int j = 0; j < 9; ++j)
                wb[j] = *reinterpret_cast<const float4*>(wp + j * 4);
            const float* wf = reinterpret_cast<const float*>(wb); // wf[dh*9+l]

            #pragma unroll
            for (int l = 0; l < LL; ++l) {
                #pragma unroll
                for (int r = 0; r < 4; ++r) {
                    const float4 xvv = xv[c & 3][r];
                    acc[r][l] += xvv.x * wf[0 * 9 + l] + xvv.y * wf[1 * 9 + l]
                               + xvv.z * wf[2 * 9 + l] + xvv.w * wf[3 * 9 + l];
                }
            }
        }
        // reduce across the 16-lane group; lane k==15 holds each total
        #pragma unroll
        for (int r = 0; r < 4; ++r)
            #pragma unroll
            for (int l = 0; l < LL; ++l) {
                float v = acc[r][l];
                v = dpp_add<0x111>(v);
                v = dpp_add<0x112>(v);
                v = dpp_add<0x114>(v);
                v = dpp_add<0x118>(v);
                acc[r][l] = v;
            }
    }

    if (k == 15) {
        #pragma unroll
        for (int r = 0; r < 4; ++r) {
            float lg[LL];
            float mx = -3.0e38f;
            #pragma unroll
            for (int l = 0; l < LL; ++l) {
                lg[l] = acc[r][l] * sc[r] + bsh[l];
                mx = fmaxf(mx, lg[l]);
            }
            float ssum = 0.f;
            #pragma unroll
            for (int l = 0; l < LL; ++l) { lg[l] = __expf(lg[l] - mx); ssum += lg[l]; }
            const float inv = 1.f / ssum;
            const int lp = wv_ * 16 + g * 4 + r;
            #pragma unroll
            for (int l = 0; l < LL; ++l) obuf[lp * LL + l] = lg[l] * inv;
        }
    }
    __syncthreads();

    // block's 64 rows are contiguous in out: 576 floats
    const int base = blockIdx.x * 64 * LL;
    for (int t = tid; t < 64 * LL; t += 256) out[base + t] = obuf[t];
}

extern "C" void kernel_launch(void* const* d_in, const int* in_sizes, int n_in,
                              void* d_out, int out_size, void* d_ws, size_t ws_size,
                              hipStream_t stream) {
    const float* x    = (const float*)d_in[0];   // [B,S,H] f32
    const int*   mask = (const int*)d_in[1];     // [B,S] i32
    const float* W    = (const float*)d_in[2];   // [H,L] f32
    const float* bias = (const float*)d_in[3];   // [L] f32
    float* out = (float*)d_out;                  // [B,S,L] f32

    fused_ner_kernel<<<BB * 8, 256, 0, stream>>>(x, mask, W, bias, out);
}

// Round 5
// 28.703 us; speedup vs baseline: 1.9192x; 1.1501x over previous
//
#include <hip/hip_runtime.h>
#include <hip/hip_bf16.h>

#define BB 64
#define SS 512
#define HH 1024
#define LL 9

// DPP row_shr shift-add: after ctrl {1,2,4,8}, lane 15 of each 16-lane row
// holds the sum of all 16 lanes. VALU-rate, no LDS pipe. (verified R2/R3)
template <int CTRL>
__device__ __forceinline__ float dpp_add(float v) {
    int s = __builtin_bit_cast(int, v);
    int r = __builtin_amdgcn_update_dpp(0, s, CTRL, 0xF, 0xF, true);
    return v + __builtin_bit_cast(float, r);
}

// Fused: per-block mask scan + gather-GEMM + softmax.
// 512 blocks x 256 threads. bat = blockIdx&63, seg = blockIdx>>6 so that
// WORKING blocks (low segs -- valid tokens compact to the head) spread
// across all 8 XCDs instead of aliasing onto XCDs 0-3 (R4 bug).
// All-pad blocks early-exit with softmax(bias) rows.
__global__ __launch_bounds__(256) void fused_ner_kernel(
    const float* __restrict__ x, const int* __restrict__ mask,
    const float* __restrict__ W, const float* __restrict__ bias,
    float* __restrict__ out) {
    __shared__ __align__(16) float Wl[HH * LL];  // 36 KB, row-major W[h][l]
    __shared__ int gidx_sh[SS];
    __shared__ int wsum[4];
    __shared__ float bsh[LL];
    __shared__ float obuf[64 * LL];

    const int tid = threadIdx.x;
    const int bat = blockIdx.x & 63;             // XCD = blockIdx%8 -> spreads segs
    const int seg = blockIdx.x >> 6;             // 0..7
    const int lane = tid & 63;
    const int wv_  = tid >> 6;                   // wave 0..3

    // ---- in-block stable-compaction scan of this batch's 512 masks ----
    const int2 mm = reinterpret_cast<const int2*>(mask + bat * SS)[tid];
    const int m0 = mm.x, m1 = mm.y;
    const int s = m0 + m1;
    int incl = s;
    #pragma unroll
    for (int off = 1; off < 64; off <<= 1) {
        int u = __shfl_up(incl, off, 64);
        if (lane >= off) incl += u;
    }
    if (lane == 63) wsum[wv_] = incl;
    __syncthreads();
    const int nv = wsum[0] + wsum[1] + wsum[2] + wsum[3];

    const size_t obase = ((size_t)bat * 8 + seg) * 64 * LL;   // 64 rows * 9

    if (seg * 64 >= nv) {
        // ---- all-pad block: rows are softmax(bias); no W, no gather ----
        float lg[LL];
        float mx = -3.0e38f;
        #pragma unroll
        for (int l = 0; l < LL; ++l) { lg[l] = bias[l]; mx = fmaxf(mx, lg[l]); }
        float ssum = 0.f;
        #pragma unroll
        for (int l = 0; l < LL; ++l) { lg[l] = __expf(lg[l] - mx); ssum += lg[l]; }
        const float inv = 1.f / ssum;
        for (int t = tid; t < 64 * LL; t += 256) {
            int l = t % LL;
            out[obase + t] = lg[l] * inv;
        }
        return;
    }

    // ---- working block: async stage W (row-major), scatter gidx ----
    #pragma unroll
    for (int i = 0; i < 9; ++i) {
        const int f4 = i * 256 + tid;            // float4 index 0..2303
        __builtin_amdgcn_global_load_lds(
            (const __attribute__((address_space(1))) void*)(W + f4 * 4),
            (__attribute__((address_space(3))) void*)(&Wl[f4 * 4]),
            16, 0, 0);
    }
    if (tid < LL) bsh[tid] = bias[tid];

    int wbase = 0;
    #pragma unroll
    for (int i = 0; i < 4; ++i) if (i < wv_) wbase += wsum[i];
    const int excl = incl - s + wbase;
    if (m0) gidx_sh[excl] = 2 * tid;
    if (m1) gidx_sh[excl + m0] = 2 * tid + 1;
    __syncthreads();                             // drains W stage; gidx ready

    // ---- gather-GEMM: 16-lane group computes 4 rows ----
    const int g = lane >> 4;                     // group 0..3 (== DPP row)
    const int k = lane & 15;
    const int pw = seg * 64 + wv_ * 16;          // wave's first local p
    const int p0 = pw + g * 4;

    float acc[4][LL];
    #pragma unroll
    for (int r = 0; r < 4; ++r)
        #pragma unroll
        for (int l = 0; l < LL; ++l) acc[r][l] = 0.f;

    float sc[4];
    const float4* xr[4];
    #pragma unroll
    for (int r = 0; r < 4; ++r) {
        const int p = p0 + r;
        const bool valid = (p < nv);
        sc[r] = valid ? 1.f : 0.f;
        const int src = valid ? gidx_sh[p] : 0;
        xr[r] = reinterpret_cast<const float4*>(x + ((size_t)bat * SS + src) * HH);
    }

    if (pw < nv) {                               // wave-uniform: any real work?
        float4 xv[4][4];                         // [slot][row] prefetch ring
        #pragma unroll
        for (int c = 0; c < 3; ++c)
            #pragma unroll
            for (int r = 0; r < 4; ++r) xv[c][r] = xr[r][c * 16 + k];

        #pragma unroll 4
        for (int c = 0; c < 16; ++c) {
            const int nc = (c + 3) & 15;         // wrap: tail reloads (L1-hit)
            #pragma unroll
            for (int r = 0; r < 4; ++r) xv[nc & 3][r] = xr[r][nc * 16 + k];

            // lane's 4x9 W sub-block: 36 contiguous floats, 9 ds_read_b128
            float4 wb[9];
            const float* wp = &Wl[(c * 16 + k) * 36];
            #pragma unroll
            for (int j = 0; j < 9; ++j)
                wb[j] = *reinterpret_cast<const float4*>(wp + j * 4);
            const float* wf = reinterpret_cast<const float*>(wb); // wf[dh*9+l]

            #pragma unroll
            for (int l = 0; l < LL; ++l) {
                #pragma unroll
                for (int r = 0; r < 4; ++r) {
                    const float4 xvv = xv[c & 3][r];
                    acc[r][l] += xvv.x * wf[0 * 9 + l] + xvv.y * wf[1 * 9 + l]
                               + xvv.z * wf[2 * 9 + l] + xvv.w * wf[3 * 9 + l];
                }
            }
        }
        // reduce across the 16-lane group; lane k==15 holds each total
        #pragma unroll
        for (int r = 0; r < 4; ++r)
            #pragma unroll
            for (int l = 0; l < LL; ++l) {
                float v = acc[r][l];
                v = dpp_add<0x111>(v);
                v = dpp_add<0x112>(v);
                v = dpp_add<0x114>(v);
                v = dpp_add<0x118>(v);
                acc[r][l] = v;
            }
    }

    if (k == 15) {
        #pragma unroll
        for (int r = 0; r < 4; ++r) {
            float lg[LL];
            float mx = -3.0e38f;
            #pragma unroll
            for (int l = 0; l < LL; ++l) {
                lg[l] = acc[r][l] * sc[r] + bsh[l];
                mx = fmaxf(mx, lg[l]);
            }
            float ssum = 0.f;
            #pragma unroll
            for (int l = 0; l < LL; ++l) { lg[l] = __expf(lg[l] - mx); ssum += lg[l]; }
            const float inv = 1.f / ssum;
            const int lp = wv_ * 16 + g * 4 + r;
            #pragma unroll
            for (int l = 0; l < LL; ++l) obuf[lp * LL + l] = lg[l] * inv;
        }
    }
    __syncthreads();

    for (int t = tid; t < 64 * LL; t += 256) out[obase + t] = obuf[t];
}

extern "C" void kernel_launch(void* const* d_in, const int* in_sizes, int n_in,
                              void* d_out, int out_size, void* d_ws, size_t ws_size,
                              hipStream_t stream) {
    const float* x    = (const float*)d_in[0];   // [B,S,H] f32
    const int*   mask = (const int*)d_in[1];     // [B,S] i32
    const float* W    = (const float*)d_in[2];   // [H,L] f32
    const float* bias = (const float*)d_in[3];   // [L] f32
    float* out = (float*)d_out;                  // [B,S,L] f32

    fused_ner_kernel<<<BB * 8, 256, 0, stream>>>(x, mask, W, bias, out);
}

// Round 6
// 24.727 us; speedup vs baseline: 2.2277x; 1.1608x over previous
//
#include <hip/hip_runtime.h>
#include <hip/hip_bf16.h>

#define BB 64
#define SS 512
#define HH 1024
#define LL 9

// DPP row_shr shift-add: after ctrl {1,2,4,8}, lane 15 of each 16-lane row
// holds the sum of all 16 lanes. VALU-rate, no LDS pipe. (verified R2-R5)
template <int CTRL>
__device__ __forceinline__ float dpp_add(float v) {
    int s = __builtin_bit_cast(int, v);
    int r = __builtin_amdgcn_update_dpp(0, s, CTRL, 0xF, 0xF, true);
    return v + __builtin_bit_cast(float, r);
}

// Fused NER head. 256 blocks (1/CU) x 512 threads (8 waves, 2/SIMD).
// Block i handles TWO mirrored 64-row segments of batch bat=i&63:
// segA = i>>6 (likely valid: tokens compact to head, nv~256) and
// segB = 7-segA (likely pad). -> every block ~64 valid + ~64 pad rows:
// statically balanced across all 256 CUs (fixes R5's 2-working-block tail).
__global__ __launch_bounds__(512) void fused_ner_kernel(
    const float* __restrict__ x, const int* __restrict__ mask,
    const float* __restrict__ W, const float* __restrict__ bias,
    float* __restrict__ out) {
    __shared__ __align__(16) float Wl[HH * LL];  // 36 KB, row-major W[h][l]
    __shared__ int gidx_sh[SS];
    __shared__ int wsum[8];
    __shared__ float bsh[LL];
    __shared__ float obuf[128 * LL];             // segA rows [0,576), segB [576,1152)

    const int tid  = threadIdx.x;
    const int bat  = blockIdx.x & 63;            // consecutive blocks -> XCD spread
    const int segA = blockIdx.x >> 6;            // 0..3
    const int segB = 7 - segA;                   // 7..4
    const int lane = tid & 63;
    const int wv_  = tid >> 6;                   // wave 0..7

    // ---- async stage W (row-major): 2304 float4, 4-5 per thread ----
    for (int f4 = tid; f4 < HH * LL / 4; f4 += 512) {
        __builtin_amdgcn_global_load_lds(
            (const __attribute__((address_space(1))) void*)(W + f4 * 4),
            (__attribute__((address_space(3))) void*)(&Wl[f4 * 4]),
            16, 0, 0);
    }
    if (tid < LL) bsh[tid] = bias[tid];

    // ---- stable-compaction scan: 512 threads, 1 token each ----
    const int m = mask[bat * SS + tid];
    int incl = m;
    #pragma unroll
    for (int off = 1; off < 64; off <<= 1) {
        int u = __shfl_up(incl, off, 64);
        if (lane >= off) incl += u;
    }
    if (lane == 63) wsum[wv_] = incl;
    __syncthreads();                             // wsum ready (also fences W stage)
    int nv = 0, wbase = 0;
    #pragma unroll
    for (int i = 0; i < 8; ++i) { if (i < wv_) wbase += wsum[i]; nv += wsum[i]; }
    const int excl = incl - m + wbase;
    if (m) gidx_sh[excl] = tid;
    __syncthreads();                             // gidx_sh + Wl readable

    // ---- gather-GEMM: wave -> 16 rows (4 groups x 4 rows) ----
    const int g = lane >> 4;                     // group 0..3 (== DPP row)
    const int k = lane & 15;
    const int segbase = (wv_ < 4 ? segA : segB) * 64;
    const int pw = segbase + (wv_ & 3) * 16;     // wave's first p
    const int p0 = pw + g * 4;

    float acc[4][LL];
    #pragma unroll
    for (int r = 0; r < 4; ++r)
        #pragma unroll
        for (int l = 0; l < LL; ++l) acc[r][l] = 0.f;

    float sc[4];
    const float4* xr[4];
    #pragma unroll
    for (int r = 0; r < 4; ++r) {
        const int p = p0 + r;
        const bool valid = (p < nv);
        sc[r] = valid ? 1.f : 0.f;
        const int src = valid ? gidx_sh[p] : 0;
        xr[r] = reinterpret_cast<const float4*>(x + ((size_t)bat * SS + src) * HH);
    }

    if (pw < nv) {                               // wave-uniform: any real work?
        float4 xv[4][4];                         // [slot][row] prefetch ring
        #pragma unroll
        for (int c = 0; c < 3; ++c)
            #pragma unroll
            for (int r = 0; r < 4; ++r) xv[c][r] = xr[r][c * 16 + k];

        #pragma unroll 4
        for (int c = 0; c < 16; ++c) {
            const int nc = (c + 3) & 15;         // wrap: tail reloads (L1-hit)
            #pragma unroll
            for (int r = 0; r < 4; ++r) xv[nc & 3][r] = xr[r][nc * 16 + k];

            // lane's 4x9 W sub-block: 36 contiguous floats, 9 ds_read_b128
            float4 wb[9];
            const float* wp = &Wl[(c * 16 + k) * 36];
            #pragma unroll
            for (int j = 0; j < 9; ++j)
                wb[j] = *reinterpret_cast<const float4*>(wp + j * 4);
            const float* wf = reinterpret_cast<const float*>(wb); // wf[dh*9+l]

            #pragma unroll
            for (int l = 0; l < LL; ++l) {
                #pragma unroll
                for (int r = 0; r < 4; ++r) {
                    const float4 xvv = xv[c & 3][r];
                    acc[r][l] += xvv.x * wf[0 * 9 + l] + xvv.y * wf[1 * 9 + l]
                               + xvv.z * wf[2 * 9 + l] + xvv.w * wf[3 * 9 + l];
                }
            }
        }
        // reduce across the 16-lane group; lane k==15 holds each total
        #pragma unroll
        for (int r = 0; r < 4; ++r)
            #pragma unroll
            for (int l = 0; l < LL; ++l) {
                float v = acc[r][l];
                v = dpp_add<0x111>(v);
                v = dpp_add<0x112>(v);
                v = dpp_add<0x114>(v);
                v = dpp_add<0x118>(v);
                acc[r][l] = v;
            }
    }

    if (k == 15) {
        #pragma unroll
        for (int r = 0; r < 4; ++r) {
            float lg[LL];
            float mx = -3.0e38f;
            #pragma unroll
            for (int l = 0; l < LL; ++l) {
                lg[l] = acc[r][l] * sc[r] + bsh[l];
                mx = fmaxf(mx, lg[l]);
            }
            float ssum = 0.f;
            #pragma unroll
            for (int l = 0; l < LL; ++l) { lg[l] = __expf(lg[l] - mx); ssum += lg[l]; }
            const float inv = 1.f / ssum;
            const int lp = wv_ * 16 + g * 4 + r;     // 0..127
            #pragma unroll
            for (int l = 0; l < LL; ++l) obuf[lp * LL + l] = lg[l] * inv;
        }
    }
    __syncthreads();

    // two contiguous 576-float spans (segA rows, segB rows)
    const size_t baseA = ((size_t)bat * SS + segA * 64) * LL;
    const size_t baseB = ((size_t)bat * SS + segB * 64) * LL;
    for (int t = tid; t < 64 * LL; t += 512) {
        out[baseA + t] = obuf[t];
        out[baseB + t] = obuf[64 * LL + t];
    }
}

extern "C" void kernel_launch(void* const* d_in, const int* in_sizes, int n_in,
                              void* d_out, int out_size, void* d_ws, size_t ws_size,
                              hipStream_t stream) {
    const float* x    = (const float*)d_in[0];   // [B,S,H] f32
    const int*   mask = (const int*)d_in[1];     // [B,S] i32
    const float* W    = (const float*)d_in[2];   // [H,L] f32
    const float* bias = (const float*)d_in[3];   // [L] f32
    float* out = (float*)d_out;                  // [B,S,L] f32

    fused_ner_kernel<<<256, 512, 0, stream>>>(x, mask, W, bias, out);
}

// Round 7
// 24.366 us; speedup vs baseline: 2.2607x; 1.0148x over previous
//
#include <hip/hip_runtime.h>
#include <hip/hip_bf16.h>

#define BB 64
#define SS 512
#define HH 1024
#define LL 9

// DPP row_shr shift-add: after ctrl {1,2,4,8}, lane 15 of each 16-lane row
// holds the sum of all 16 lanes. VALU-rate, no LDS pipe. (verified R2-R6)
template <int CTRL>
__device__ __forceinline__ float dpp_add(float v) {
    int s = __builtin_bit_cast(int, v);
    int r = __builtin_amdgcn_update_dpp(0, s, CTRL, 0xF, 0xF, true);
    return v + __builtin_bit_cast(float, r);
}

// Fused NER head. 256 blocks (1/CU) x 512 threads (8 waves, 2/SIMD).
// Block i: batch bat=i&63, mirrored segments segA=i>>6 / segB=7-segA.
// NEW (R7): valid rows form a work queue (vA from segA + vB from segB);
// queue entries go round-robin to all 32 groups (2 rows each) so ALL 8
// waves work (2 working waves/SIMD -> TLP hides HBM latency; R6 had 1).
// Ring prefetch depth 8. Pad rows get softmax(bias) in the output phase.
__global__ __launch_bounds__(512) void fused_ner_kernel(
    const float* __restrict__ x, const int* __restrict__ mask,
    const float* __restrict__ W, const float* __restrict__ bias,
    float* __restrict__ out) {
    __shared__ __align__(16) float Wl[HH * LL];  // 36 KB, row-major W[h][l]
    __shared__ int gidx_sh[SS];
    __shared__ int wsum[8];
    __shared__ float bsh[LL];
    __shared__ float obuf[128 * LL];             // indexed by queue pos j

    const int tid  = threadIdx.x;
    const int bat  = blockIdx.x & 63;            // consecutive blocks -> XCD spread
    const int segA = blockIdx.x >> 6;            // 0..3
    const int segB = 7 - segA;                   // 7..4
    const int lane = tid & 63;
    const int wv_  = tid >> 6;                   // wave 0..7

    // ---- async stage W (row-major): 2304 float4 ----
    for (int f4 = tid; f4 < HH * LL / 4; f4 += 512) {
        __builtin_amdgcn_global_load_lds(
            (const __attribute__((address_space(1))) void*)(W + f4 * 4),
            (__attribute__((address_space(3))) void*)(&Wl[f4 * 4]),
            16, 0, 0);
    }
    if (tid < LL) bsh[tid] = bias[tid];

    // ---- stable-compaction scan: 512 threads, 1 token each ----
    const int m = mask[bat * SS + tid];
    int incl = m;
    #pragma unroll
    for (int off = 1; off < 64; off <<= 1) {
        int u = __shfl_up(incl, off, 64);
        if (lane >= off) incl += u;
    }
    if (lane == 63) wsum[wv_] = incl;
    __syncthreads();                             // wsum ready; W stage drained
    int nv = 0, wbase = 0;
    #pragma unroll
    for (int i = 0; i < 8; ++i) { if (i < wv_) wbase += wsum[i]; nv += wsum[i]; }
    const int excl = incl - m + wbase;
    if (m) gidx_sh[excl] = tid;
    __syncthreads();                             // gidx_sh readable

    const int g = lane >> 4;                     // group 0..3 (== DPP row)
    const int k = lane & 15;
    const int G = wv_ * 4 + g;                   // 0..31
    const int vA = min(max(nv - segA * 64, 0), 64);
    const int vB = min(max(nv - segB * 64, 0), 64);
    const int nwork = vA + vB;                   // valid rows in this block

    #pragma unroll 1
    for (int pass = 0; pass < 2; ++pass) {
        const int jbase = pass * 64;
        if (jbase + wv_ * 8 >= nwork) break;     // wave-uniform skip

        float acc[2][LL];
        #pragma unroll
        for (int r = 0; r < 2; ++r)
            #pragma unroll
            for (int l = 0; l < LL; ++l) acc[r][l] = 0.f;

        float sc[2];
        const float4* xr[2];
        int jj[2];
        #pragma unroll
        for (int r = 0; r < 2; ++r) {
            const int j = jbase + 2 * G + r;     // queue position
            jj[r] = j;
            const bool valid = (j < nwork);
            sc[r] = valid ? 1.f : 0.f;
            const int p = (j < vA) ? segA * 64 + j : segB * 64 + (j - vA);
            const int src = gidx_sh[valid ? p : 0];
            xr[r] = reinterpret_cast<const float4*>(x + ((size_t)bat * SS + src) * HH);
        }

        float4 xv[8][2];                         // depth-8 prefetch ring
        #pragma unroll
        for (int c = 0; c < 8; ++c)
            #pragma unroll
            for (int r = 0; r < 2; ++r) xv[c][r] = xr[r][c * 16 + k];

        #pragma unroll
        for (int c = 0; c < 16; ++c) {
            const float4 xv0 = xv[c & 7][0];
            const float4 xv1 = xv[c & 7][1];
            if (c < 8) {                         // refill slot just consumed
                #pragma unroll
                for (int r = 0; r < 2; ++r) xv[c & 7][r] = xr[r][(c + 8) * 16 + k];
            }
            // lane's 4x9 W sub-block: 36 contiguous floats, 9 ds_read_b128
            float4 wb[9];
            const float* wp = &Wl[(c * 16 + k) * 36];
            #pragma unroll
            for (int j2 = 0; j2 < 9; ++j2)
                wb[j2] = *reinterpret_cast<const float4*>(wp + j2 * 4);
            const float* wf = reinterpret_cast<const float*>(wb); // wf[dh*9+l]

            #pragma unroll
            for (int l = 0; l < LL; ++l) {
                acc[0][l] += xv0.x * wf[0 * 9 + l] + xv0.y * wf[1 * 9 + l]
                           + xv0.z * wf[2 * 9 + l] + xv0.w * wf[3 * 9 + l];
                acc[1][l] += xv1.x * wf[0 * 9 + l] + xv1.y * wf[1 * 9 + l]
                           + xv1.z * wf[2 * 9 + l] + xv1.w * wf[3 * 9 + l];
            }
        }

        // reduce across the 16-lane group; lane k==15 holds each total
        #pragma unroll
        for (int r = 0; r < 2; ++r)
            #pragma unroll
            for (int l = 0; l < LL; ++l) {
                float v = acc[r][l];
                v = dpp_add<0x111>(v);
                v = dpp_add<0x112>(v);
                v = dpp_add<0x114>(v);
                v = dpp_add<0x118>(v);
                acc[r][l] = v;
            }

        if (k == 15) {
            #pragma unroll
            for (int r = 0; r < 2; ++r) {
                float lg[LL];
                float mx = -3.0e38f;
                #pragma unroll
                for (int l = 0; l < LL; ++l) {
                    lg[l] = acc[r][l] * sc[r] + bsh[l];
                    mx = fmaxf(mx, lg[l]);
                }
                float ssum = 0.f;
                #pragma unroll
                for (int l = 0; l < LL; ++l) { lg[l] = __expf(lg[l] - mx); ssum += lg[l]; }
                const float inv = 1.f / ssum;
                #pragma unroll
                for (int l = 0; l < LL; ++l) obuf[jj[r] * LL + l] = lg[l] * inv;
            }
        }
    }

    // softmax(bias) for pad slots (every thread, registers only)
    float bs[LL];
    float mxb = -3.0e38f;
    #pragma unroll
    for (int l = 0; l < LL; ++l) { bs[l] = bsh[l]; mxb = fmaxf(mxb, bs[l]); }
    float sb = 0.f;
    #pragma unroll
    for (int l = 0; l < LL; ++l) { bs[l] = __expf(bs[l] - mxb); sb += bs[l]; }
    const float invb = 1.f / sb;

    __syncthreads();                             // obuf complete

    // two contiguous 576-float spans; queue pos for segA row t/9 is the row
    // itself, for segB row it's vA+row.
    const size_t baseA = ((size_t)bat * SS + segA * 64) * LL;
    const size_t baseB = ((size_t)bat * SS + segB * 64) * LL;
    for (int t = tid; t < 64 * LL; t += 512) {
        const int row = t / LL;
        const int l   = t - row * LL;
        out[baseA + t] = (row < vA) ? obuf[t] : bs[l] * invb;
        out[baseB + t] = (row < vB) ? obuf[vA * LL + t] : bs[l] * invb;
    }
}

extern "C" void kernel_launch(void* const* d_in, const int* in_sizes, int n_in,
                              void* d_out, int out_size, void* d_ws, size_t ws_size,
                              hipStream_t stream) {
    const float* x    = (const float*)d_in[0];   // [B,S,H] f32
    const int*   mask = (const int*)d_in[1];     // [B,S] i32
    const float* W    = (const float*)d_in[2];   // [H,L] f32
    const float* bias = (const float*)d_in[3];   // [L] f32
    float* out = (float*)d_out;                  // [B,S,L] f32

    fused_ner_kernel<<<256, 512, 0, stream>>>(x, mask, W, bias, out);
}